// Round 1
// baseline (276.258 us; speedup 1.0000x reference)
//
#include <hip/hip_runtime.h>
#include <hip/hip_bf16.h>
#include <math.h>

#define BATCH 16
#define CH    256
#define HDIM  32
#define WDIM  32
#define HW    1024
#define NS    256
#define NH    16
#define DH    16

// ---------------------------------------------------------------------------
// conv1x1: Y[b,o,p] = sum_i W[o,i] * X[b,i,p] + bias[o]   (optional BN epilogue)
// 64x64 tile, 256 threads, 4x4 microtile, K-chunk = 16
// ---------------------------------------------------------------------------
template<int P, bool BN>
__global__ __launch_bounds__(256) void conv1x1_k(
    const float* __restrict__ Wm, const float* __restrict__ X,
    const float* __restrict__ bias, float* __restrict__ Y,
    const float* __restrict__ bn_g, const float* __restrict__ bn_b,
    const float* __restrict__ bn_m, const float* __restrict__ bn_v)
{
    const int b  = blockIdx.z;
    const int o0 = blockIdx.y * 64;
    const int p0 = blockIdx.x * 64;
    __shared__ float Ws[16][64];   // [k][o]
    __shared__ float Xs[16][64];   // [k][p]
    const int t  = threadIdx.x;
    const int tr = t >> 4;         // 0..15  (o-dim)
    const int tc = t & 15;         // 0..15  (p-dim)
    float acc[4][4] = {};
    const float* Xb = X + (size_t)b * CH * P;

    for (int k0 = 0; k0 < CH; k0 += 16) {
        {   // W tile 64x16 -> Ws[k][o]
            int r = t >> 2;          // 0..63
            int c = (t & 3) << 2;    // 0,4,8,12
            float4 w4 = *(const float4*)&Wm[(size_t)(o0 + r) * CH + k0 + c];
            Ws[c + 0][r] = w4.x; Ws[c + 1][r] = w4.y;
            Ws[c + 2][r] = w4.z; Ws[c + 3][r] = w4.w;
        }
        {   // X tile 16x64 -> Xs[k][p]
            int r = t >> 4;          // 0..15
            int c = (t & 15) << 2;   // 0..60
            float4 x4 = *(const float4*)&Xb[(size_t)(k0 + r) * P + p0 + c];
            *(float4*)&Xs[r][c] = x4;
        }
        __syncthreads();
        #pragma unroll
        for (int kk = 0; kk < 16; ++kk) {
            float4 a4 = *(const float4*)&Ws[kk][tr * 4];
            float4 x4 = *(const float4*)&Xs[kk][tc * 4];
            acc[0][0] += a4.x * x4.x; acc[0][1] += a4.x * x4.y;
            acc[0][2] += a4.x * x4.z; acc[0][3] += a4.x * x4.w;
            acc[1][0] += a4.y * x4.x; acc[1][1] += a4.y * x4.y;
            acc[1][2] += a4.y * x4.z; acc[1][3] += a4.y * x4.w;
            acc[2][0] += a4.z * x4.x; acc[2][1] += a4.z * x4.y;
            acc[2][2] += a4.z * x4.z; acc[2][3] += a4.z * x4.w;
            acc[3][0] += a4.w * x4.x; acc[3][1] += a4.w * x4.y;
            acc[3][2] += a4.w * x4.z; acc[3][3] += a4.w * x4.w;
        }
        __syncthreads();
    }

    #pragma unroll
    for (int i = 0; i < 4; ++i) {
        int o = o0 + tr * 4 + i;
        float bs = bias[o];
        float scale = 1.0f, shift = 0.0f;
        if (BN) {
            float inv = rsqrtf(bn_v[o] + 1e-5f);
            scale = bn_g[o] * inv;
            shift = bn_b[o] - bn_m[o] * scale;
        }
        float4 r;
        r.x = acc[i][0] + bs; r.y = acc[i][1] + bs;
        r.z = acc[i][2] + bs; r.w = acc[i][3] + bs;
        if (BN) {
            r.x = r.x * scale + shift; r.y = r.y * scale + shift;
            r.z = r.z * scale + shift; r.w = r.w * scale + shift;
        }
        *(float4*)&Y[((size_t)b * CH + o) * P + p0 + tc * 4] = r;
    }
}

// ---------------------------------------------------------------------------
// depthwise 9x9 conv, stride 2, pad 4:  q[B,C,32,32] -> off[B,C,16,16]
// one block per (b,c) plane, plane staged in LDS
// ---------------------------------------------------------------------------
__global__ __launch_bounds__(256) void dwconv_k(
    const float* __restrict__ q, const float* __restrict__ w,
    const float* __restrict__ bias, float* __restrict__ off)
{
    int bc = blockIdx.x;
    int c  = bc & (CH - 1);
    __shared__ float plane[HW];
    __shared__ float kw[81];
    int t = threadIdx.x;
    const float* qp = q + (size_t)bc * HW;
    #pragma unroll
    for (int j = t; j < HW; j += 256) plane[j] = qp[j];
    if (t < 81) kw[t] = w[c * 81 + t];
    __syncthreads();
    int hk = t >> 4, wk = t & 15;
    float s = bias[c];
    int yb = hk * 2 - 4, xb = wk * 2 - 4;
    #pragma unroll
    for (int dy = 0; dy < 9; ++dy) {
        int yy = yb + dy;
        if ((unsigned)yy < 32u) {
            #pragma unroll
            for (int dx = 0; dx < 9; ++dx) {
                int xx = xb + dx;
                if ((unsigned)xx < 32u) s += kw[dy * 9 + dx] * plane[yy * 32 + xx];
            }
        }
    }
    off[(size_t)bc * NS + t] = s;
}

// ---------------------------------------------------------------------------
// LN(channel) + GELU + 2-channel projection + ref + tanh -> pos[B,NS,2] (y,x)
// one block per (b, spatial) position; 256 threads = channels
// ---------------------------------------------------------------------------
__device__ inline void block_reduce2(float& a, float& b, int t, float* sbuf)
{
    #pragma unroll
    for (int o = 32; o > 0; o >>= 1) {
        a += __shfl_down(a, o);
        b += __shfl_down(b, o);
    }
    int w = t >> 6;
    if ((t & 63) == 0) { sbuf[w * 2] = a; sbuf[w * 2 + 1] = b; }
    __syncthreads();
    a = sbuf[0] + sbuf[2] + sbuf[4] + sbuf[6];
    b = sbuf[1] + sbuf[3] + sbuf[5] + sbuf[7];
    __syncthreads();
}

__global__ __launch_bounds__(256) void lnoff_k(
    const float* __restrict__ off, const float* __restrict__ ln_g,
    const float* __restrict__ ln_b, const float* __restrict__ pw,
    float* __restrict__ pos)
{
    __shared__ float sbuf[8];
    int bs = blockIdx.x;
    int b = bs >> 8, s = bs & 255;
    int c = threadIdx.x;
    float v = off[((size_t)(b * CH + c)) * NS + s];
    float a = v, q2 = v * v;
    block_reduce2(a, q2, c, sbuf);
    float mean = a * (1.0f / 256.0f);
    float var  = q2 * (1.0f / 256.0f) - mean * mean;
    float xn = (v - mean) * rsqrtf(var + 1e-5f) * ln_g[c] + ln_b[c];
    float g = 0.5f * xn * (1.0f + erff(xn * 0.70710678118654752f));
    float d0 = g * pw[c];
    float d1 = g * pw[CH + c];
    block_reduce2(d0, d1, c, sbuf);
    if (c == 0) {
        int hk = s >> 4, wk = s & 15;
        float ry = ((hk + 0.5f) / 16.0f) * 2.0f - 1.0f;
        float rx = ((wk + 0.5f) / 16.0f) * 2.0f - 1.0f;
        pos[bs * 2 + 0] = tanhf(d0 + ry);
        pos[bs * 2 + 1] = tanhf(d1 + rx);
    }
}

// ---------------------------------------------------------------------------
// bilinear grid sample (align_corners=True, zeros pad): xs[B,C,NS]
// one block per (b,s); 256 threads = channels
// ---------------------------------------------------------------------------
__global__ __launch_bounds__(256) void gsample_k(
    const float* __restrict__ x, const float* __restrict__ pos,
    float* __restrict__ xs)
{
    int bs = blockIdx.x;
    int b = bs >> 8, s = bs & 255;
    float py = pos[bs * 2 + 0];
    float px = pos[bs * 2 + 1];
    float gx = (px + 1.0f) * 0.5f * 31.0f;
    float gy = (py + 1.0f) * 0.5f * 31.0f;
    float x0f = floorf(gx), y0f = floorf(gy);
    int ix = (int)x0f, iy = (int)y0f;
    float wx1 = gx - x0f, wx0 = 1.0f - wx1;
    float wy1 = gy - y0f, wy0 = 1.0f - wy1;
    int c = threadIdx.x;
    const float* img = x + ((size_t)b * CH + c) * HW;
    float v00 = ((unsigned)iy < 32u && (unsigned)ix < 32u) ? img[iy * 32 + ix] : 0.0f;
    float v01 = ((unsigned)iy < 32u && (unsigned)(ix + 1) < 32u) ? img[iy * 32 + ix + 1] : 0.0f;
    float v10 = ((unsigned)(iy + 1) < 32u && (unsigned)ix < 32u) ? img[(iy + 1) * 32 + ix] : 0.0f;
    float v11 = ((unsigned)(iy + 1) < 32u && (unsigned)(ix + 1) < 32u) ? img[(iy + 1) * 32 + ix + 1] : 0.0f;
    float v = wy0 * wx0 * v00 + wy0 * wx1 * v01 + wy1 * wx0 * v10 + wy1 * wx1 * v11;
    xs[((size_t)b * CH + c) * NS + s] = v;
}

// ---------------------------------------------------------------------------
// attention: per (b,head): S = (Q^T K)/4, softmax_n, O = S V^T
// one block per bh; K,V staged transposed in LDS as [n][d]; 4 rows/thread,
// online softmax with rare-rescale branch
// ---------------------------------------------------------------------------
__global__ __launch_bounds__(256) void attn_k(
    const float* __restrict__ q, const float* __restrict__ K,
    const float* __restrict__ V, float* __restrict__ out)
{
    int bh = blockIdx.x;
    __shared__ float Ks[NS * 16];
    __shared__ float Vs[NS * 16];
    int t = threadIdx.x;
    {
        int d  = t >> 4;
        int n0 = (t & 15) << 4;
        const float* kp = K + ((size_t)bh * 16 + d) * NS + n0;
        const float* vp = V + ((size_t)bh * 16 + d) * NS + n0;
        #pragma unroll
        for (int j = 0; j < 16; ++j) Ks[(n0 + j) * 16 + d] = kp[j];
        #pragma unroll
        for (int j = 0; j < 16; ++j) Vs[(n0 + j) * 16 + d] = vp[j];
    }
    __syncthreads();

    float qreg[4][16];
    #pragma unroll
    for (int r = 0; r < 4; ++r) {
        int m = (r << 8) + t;
        #pragma unroll
        for (int d = 0; d < 16; ++d)
            qreg[r][d] = q[((size_t)bh * 16 + d) * HW + m] * 0.25f;
    }

    float mx[4] = {-1e30f, -1e30f, -1e30f, -1e30f};
    float l[4]  = {0.f, 0.f, 0.f, 0.f};
    float acc[4][16] = {};

    for (int n = 0; n < NS; ++n) {
        const float4* kp4 = (const float4*)&Ks[n * 16];
        float4 k0 = kp4[0], k1 = kp4[1], k2 = kp4[2], k3 = kp4[3];
        const float4* vp4 = (const float4*)&Vs[n * 16];
        float4 v0 = vp4[0], v1 = vp4[1], v2 = vp4[2], v3 = vp4[3];
        #pragma unroll
        for (int r = 0; r < 4; ++r) {
            float s =
                qreg[r][ 0] * k0.x + qreg[r][ 1] * k0.y + qreg[r][ 2] * k0.z + qreg[r][ 3] * k0.w
              + qreg[r][ 4] * k1.x + qreg[r][ 5] * k1.y + qreg[r][ 6] * k1.z + qreg[r][ 7] * k1.w
              + qreg[r][ 8] * k2.x + qreg[r][ 9] * k2.y + qreg[r][10] * k2.z + qreg[r][11] * k2.w
              + qreg[r][12] * k3.x + qreg[r][13] * k3.y + qreg[r][14] * k3.z + qreg[r][15] * k3.w;
            if (s > mx[r]) {
                float al = __expf(mx[r] - s);
                mx[r] = s;
                l[r] *= al;
                #pragma unroll
                for (int d = 0; d < 16; ++d) acc[r][d] *= al;
            }
            float p = __expf(s - mx[r]);
            l[r] += p;
            acc[r][ 0] += p * v0.x; acc[r][ 1] += p * v0.y; acc[r][ 2] += p * v0.z; acc[r][ 3] += p * v0.w;
            acc[r][ 4] += p * v1.x; acc[r][ 5] += p * v1.y; acc[r][ 6] += p * v1.z; acc[r][ 7] += p * v1.w;
            acc[r][ 8] += p * v2.x; acc[r][ 9] += p * v2.y; acc[r][10] += p * v2.z; acc[r][11] += p * v2.w;
            acc[r][12] += p * v3.x; acc[r][13] += p * v3.y; acc[r][14] += p * v3.z; acc[r][15] += p * v3.w;
        }
    }

    #pragma unroll
    for (int r = 0; r < 4; ++r) {
        int m = (r << 8) + t;
        float inv = 1.0f / l[r];
        #pragma unroll
        for (int d = 0; d < 16; ++d)
            out[((size_t)bh * 16 + d) * HW + m] = acc[r][d] * inv;
    }
}

// ---------------------------------------------------------------------------
extern "C" void kernel_launch(void* const* d_in, const int* in_sizes, int n_in,
                              void* d_out, int out_size, void* d_ws, size_t ws_size,
                              hipStream_t stream)
{
    const float* x        = (const float*)d_in[0];
    const float* wq       = (const float*)d_in[1];
    const float* bq       = (const float*)d_in[2];
    const float* off_dw_w = (const float*)d_in[3];
    const float* off_dw_b = (const float*)d_in[4];
    const float* ln_g     = (const float*)d_in[5];
    const float* ln_b     = (const float*)d_in[6];
    const float* off_pw_w = (const float*)d_in[7];
    const float* wk       = (const float*)d_in[8];
    const float* bk       = (const float*)d_in[9];
    const float* wv       = (const float*)d_in[10];
    const float* bv       = (const float*)d_in[11];
    const float* wo       = (const float*)d_in[12];
    const float* bo       = (const float*)d_in[13];
    const float* bn_g     = (const float*)d_in[14];
    const float* bn_b     = (const float*)d_in[15];
    const float* bn_m     = (const float*)d_in[16];
    const float* bn_v     = (const float*)d_in[17];

    float* ws  = (float*)d_ws;
    float* q   = ws;                       // 16*256*1024 = 4194304
    float* off = q   + 4194304;            // 16*256*256  = 1048576
    float* pos = off + 1048576;            // 16*256*2    = 8192
    float* xs  = pos + 8192;               // 1048576
    float* kb  = xs  + 1048576;            // 1048576
    float* vb  = kb  + 1048576;            // 1048576
    float* ao  = vb  + 1048576;            // 4194304

    conv1x1_k<HW, false><<<dim3(16, 4, BATCH), 256, 0, stream>>>(
        wq, x, bq, q, nullptr, nullptr, nullptr, nullptr);
    dwconv_k<<<BATCH * CH, 256, 0, stream>>>(q, off_dw_w, off_dw_b, off);
    lnoff_k<<<BATCH * NS, 256, 0, stream>>>(off, ln_g, ln_b, off_pw_w, pos);
    gsample_k<<<BATCH * NS, 256, 0, stream>>>(x, pos, xs);
    conv1x1_k<NS, false><<<dim3(4, 4, BATCH), 256, 0, stream>>>(
        wk, xs, bk, kb, nullptr, nullptr, nullptr, nullptr);
    conv1x1_k<NS, false><<<dim3(4, 4, BATCH), 256, 0, stream>>>(
        wv, xs, bv, vb, nullptr, nullptr, nullptr, nullptr);
    attn_k<<<BATCH * NH, 256, 0, stream>>>(q, kb, vb, ao);
    conv1x1_k<HW, true><<<dim3(16, 4, BATCH), 256, 0, stream>>>(
        wo, ao, bo, (float*)d_out, bn_g, bn_b, bn_m, bn_v);
}

// Round 2
// 255.014 us; speedup vs baseline: 1.0833x; 1.0833x over previous
//
#include <hip/hip_runtime.h>
#include <hip/hip_bf16.h>
#include <math.h>

#define BATCH 16
#define CH    256
#define HDIM  32
#define WDIM  32
#define HW    1024
#define NS    256
#define NH    16
#define DH    16

// ---------------------------------------------------------------------------
// conv1x1: Y[b,o,p] = sum_i W[o,i] * X[b,i,p] + bias[o]   (optional BN epilogue)
// 64x64 tile, 256 threads, 4x4 microtile, K-chunk = 16
// ---------------------------------------------------------------------------
template<int P, bool BN>
__global__ __launch_bounds__(256) void conv1x1_k(
    const float* __restrict__ Wm, const float* __restrict__ X,
    const float* __restrict__ bias, float* __restrict__ Y,
    const float* __restrict__ bn_g, const float* __restrict__ bn_b,
    const float* __restrict__ bn_m, const float* __restrict__ bn_v)
{
    const int b  = blockIdx.z;
    const int o0 = blockIdx.y * 64;
    const int p0 = blockIdx.x * 64;
    __shared__ float Ws[16][64];   // [k][o]
    __shared__ float Xs[16][64];   // [k][p]
    const int t  = threadIdx.x;
    const int tr = t >> 4;         // 0..15  (o-dim)
    const int tc = t & 15;         // 0..15  (p-dim)
    float acc[4][4] = {};
    const float* Xb = X + (size_t)b * CH * P;

    for (int k0 = 0; k0 < CH; k0 += 16) {
        {   // W tile 64x16 -> Ws[k][o]
            int r = t >> 2;          // 0..63
            int c = (t & 3) << 2;    // 0,4,8,12
            float4 w4 = *(const float4*)&Wm[(size_t)(o0 + r) * CH + k0 + c];
            Ws[c + 0][r] = w4.x; Ws[c + 1][r] = w4.y;
            Ws[c + 2][r] = w4.z; Ws[c + 3][r] = w4.w;
        }
        {   // X tile 16x64 -> Xs[k][p]
            int r = t >> 4;          // 0..15
            int c = (t & 15) << 2;   // 0..60
            float4 x4 = *(const float4*)&Xb[(size_t)(k0 + r) * P + p0 + c];
            *(float4*)&Xs[r][c] = x4;
        }
        __syncthreads();
        #pragma unroll
        for (int kk = 0; kk < 16; ++kk) {
            float4 a4 = *(const float4*)&Ws[kk][tr * 4];
            float4 x4 = *(const float4*)&Xs[kk][tc * 4];
            acc[0][0] += a4.x * x4.x; acc[0][1] += a4.x * x4.y;
            acc[0][2] += a4.x * x4.z; acc[0][3] += a4.x * x4.w;
            acc[1][0] += a4.y * x4.x; acc[1][1] += a4.y * x4.y;
            acc[1][2] += a4.y * x4.z; acc[1][3] += a4.y * x4.w;
            acc[2][0] += a4.z * x4.x; acc[2][1] += a4.z * x4.y;
            acc[2][2] += a4.z * x4.z; acc[2][3] += a4.z * x4.w;
            acc[3][0] += a4.w * x4.x; acc[3][1] += a4.w * x4.y;
            acc[3][2] += a4.w * x4.z; acc[3][3] += a4.w * x4.w;
        }
        __syncthreads();
    }

    #pragma unroll
    for (int i = 0; i < 4; ++i) {
        int o = o0 + tr * 4 + i;
        float bs = bias[o];
        float scale = 1.0f, shift = 0.0f;
        if (BN) {
            float inv = rsqrtf(bn_v[o] + 1e-5f);
            scale = bn_g[o] * inv;
            shift = bn_b[o] - bn_m[o] * scale;
        }
        float4 r;
        r.x = acc[i][0] + bs; r.y = acc[i][1] + bs;
        r.z = acc[i][2] + bs; r.w = acc[i][3] + bs;
        if (BN) {
            r.x = r.x * scale + shift; r.y = r.y * scale + shift;
            r.z = r.z * scale + shift; r.w = r.w * scale + shift;
        }
        *(float4*)&Y[((size_t)b * CH + o) * P + p0 + tc * 4] = r;
    }
}

// ---------------------------------------------------------------------------
// depthwise 9x9 conv, stride 2, pad 4:  q[B,C,32,32] -> off[B,C,16,16]
// ---------------------------------------------------------------------------
__global__ __launch_bounds__(256) void dwconv_k(
    const float* __restrict__ q, const float* __restrict__ w,
    const float* __restrict__ bias, float* __restrict__ off)
{
    int bc = blockIdx.x;
    int c  = bc & (CH - 1);
    __shared__ float plane[HW];
    __shared__ float kw[81];
    int t = threadIdx.x;
    const float* qp = q + (size_t)bc * HW;
    #pragma unroll
    for (int j = t; j < HW; j += 256) plane[j] = qp[j];
    if (t < 81) kw[t] = w[c * 81 + t];
    __syncthreads();
    int hk = t >> 4, wk = t & 15;
    float s = bias[c];
    int yb = hk * 2 - 4, xb = wk * 2 - 4;
    #pragma unroll
    for (int dy = 0; dy < 9; ++dy) {
        int yy = yb + dy;
        if ((unsigned)yy < 32u) {
            #pragma unroll
            for (int dx = 0; dx < 9; ++dx) {
                int xx = xb + dx;
                if ((unsigned)xx < 32u) s += kw[dy * 9 + dx] * plane[yy * 32 + xx];
            }
        }
    }
    off[(size_t)bc * NS + t] = s;
}

// ---------------------------------------------------------------------------
// LN(channel) + GELU + 2-channel projection + ref + tanh -> pos[B,NS,2] (y,x)
// ---------------------------------------------------------------------------
__device__ inline void block_reduce2(float& a, float& b, int t, float* sbuf)
{
    #pragma unroll
    for (int o = 32; o > 0; o >>= 1) {
        a += __shfl_down(a, o);
        b += __shfl_down(b, o);
    }
    int w = t >> 6;
    if ((t & 63) == 0) { sbuf[w * 2] = a; sbuf[w * 2 + 1] = b; }
    __syncthreads();
    a = sbuf[0] + sbuf[2] + sbuf[4] + sbuf[6];
    b = sbuf[1] + sbuf[3] + sbuf[5] + sbuf[7];
    __syncthreads();
}

__global__ __launch_bounds__(256) void lnoff_k(
    const float* __restrict__ off, const float* __restrict__ ln_g,
    const float* __restrict__ ln_b, const float* __restrict__ pw,
    float* __restrict__ pos)
{
    __shared__ float sbuf[8];
    int bs = blockIdx.x;
    int b = bs >> 8, s = bs & 255;
    int c = threadIdx.x;
    float v = off[((size_t)(b * CH + c)) * NS + s];
    float a = v, q2 = v * v;
    block_reduce2(a, q2, c, sbuf);
    float mean = a * (1.0f / 256.0f);
    float var  = q2 * (1.0f / 256.0f) - mean * mean;
    float xn = (v - mean) * rsqrtf(var + 1e-5f) * ln_g[c] + ln_b[c];
    float g = 0.5f * xn * (1.0f + erff(xn * 0.70710678118654752f));
    float d0 = g * pw[c];
    float d1 = g * pw[CH + c];
    block_reduce2(d0, d1, c, sbuf);
    if (c == 0) {
        int hk = s >> 4, wk = s & 15;
        float ry = ((hk + 0.5f) / 16.0f) * 2.0f - 1.0f;
        float rx = ((wk + 0.5f) / 16.0f) * 2.0f - 1.0f;
        pos[bs * 2 + 0] = tanhf(d0 + ry);
        pos[bs * 2 + 1] = tanhf(d1 + rx);
    }
}

// ---------------------------------------------------------------------------
// bilinear grid sample (align_corners=True, zeros pad): xs[B,C,NS]
// ---------------------------------------------------------------------------
__global__ __launch_bounds__(256) void gsample_k(
    const float* __restrict__ x, const float* __restrict__ pos,
    float* __restrict__ xs)
{
    int bs = blockIdx.x;
    int b = bs >> 8, s = bs & 255;
    float py = pos[bs * 2 + 0];
    float px = pos[bs * 2 + 1];
    float gx = (px + 1.0f) * 0.5f * 31.0f;
    float gy = (py + 1.0f) * 0.5f * 31.0f;
    float x0f = floorf(gx), y0f = floorf(gy);
    int ix = (int)x0f, iy = (int)y0f;
    float wx1 = gx - x0f, wx0 = 1.0f - wx1;
    float wy1 = gy - y0f, wy0 = 1.0f - wy1;
    int c = threadIdx.x;
    const float* img = x + ((size_t)b * CH + c) * HW;
    float v00 = ((unsigned)iy < 32u && (unsigned)ix < 32u) ? img[iy * 32 + ix] : 0.0f;
    float v01 = ((unsigned)iy < 32u && (unsigned)(ix + 1) < 32u) ? img[iy * 32 + ix + 1] : 0.0f;
    float v10 = ((unsigned)(iy + 1) < 32u && (unsigned)ix < 32u) ? img[(iy + 1) * 32 + ix] : 0.0f;
    float v11 = ((unsigned)(iy + 1) < 32u && (unsigned)(ix + 1) < 32u) ? img[(iy + 1) * 32 + ix + 1] : 0.0f;
    float v = wy0 * wx0 * v00 + wy0 * wx1 * v01 + wy1 * wx0 * v10 + wy1 * wx1 * v11;
    xs[((size_t)b * CH + c) * NS + s] = v;
}

// ---------------------------------------------------------------------------
// attention: per (b,head): S = (Q^T K)/4, softmax_n, O = S V^T
// grid = B*NH*4 blocks; each block owns 256 query rows (1 row/thread).
// K,V staged transposed in LDS as [n][d] (float4 broadcast reads).
// ---------------------------------------------------------------------------
__global__ __launch_bounds__(256) void attn_k(
    const float* __restrict__ q, const float* __restrict__ K,
    const float* __restrict__ V, float* __restrict__ out)
{
    int bh   = blockIdx.x >> 2;    // 0..255
    int mblk = blockIdx.x & 3;     // 0..3 query-row chunk
    __shared__ float Ks[NS * 16];
    __shared__ float Vs[NS * 16];
    int t = threadIdx.x;
    {
        int d  = t >> 4;
        int n0 = (t & 15) << 4;
        const float* kp = K + ((size_t)bh * 16 + d) * NS + n0;
        const float* vp = V + ((size_t)bh * 16 + d) * NS + n0;
        #pragma unroll
        for (int j = 0; j < 16; ++j) Ks[(n0 + j) * 16 + d] = kp[j];
        #pragma unroll
        for (int j = 0; j < 16; ++j) Vs[(n0 + j) * 16 + d] = vp[j];
    }
    __syncthreads();

    const int m = (mblk << 8) + t;
    float qreg[16];
    #pragma unroll
    for (int d = 0; d < 16; ++d)
        qreg[d] = q[((size_t)bh * 16 + d) * HW + m] * 0.25f;

    float mx = -1e30f, l = 0.0f;
    float acc[16] = {};

    for (int n = 0; n < NS; ++n) {
        const float4* kp4 = (const float4*)&Ks[n * 16];
        float4 k0 = kp4[0], k1 = kp4[1], k2 = kp4[2], k3 = kp4[3];
        float s =
            qreg[ 0] * k0.x + qreg[ 1] * k0.y + qreg[ 2] * k0.z + qreg[ 3] * k0.w
          + qreg[ 4] * k1.x + qreg[ 5] * k1.y + qreg[ 6] * k1.z + qreg[ 7] * k1.w
          + qreg[ 8] * k2.x + qreg[ 9] * k2.y + qreg[10] * k2.z + qreg[11] * k2.w
          + qreg[12] * k3.x + qreg[13] * k3.y + qreg[14] * k3.z + qreg[15] * k3.w;
        if (s > mx) {
            float al = __expf(mx - s);
            mx = s;
            l *= al;
            #pragma unroll
            for (int d = 0; d < 16; ++d) acc[d] *= al;
        }
        float p = __expf(s - mx);
        l += p;
        const float4* vp4 = (const float4*)&Vs[n * 16];
        float4 v0 = vp4[0], v1 = vp4[1], v2 = vp4[2], v3 = vp4[3];
        acc[ 0] += p * v0.x; acc[ 1] += p * v0.y; acc[ 2] += p * v0.z; acc[ 3] += p * v0.w;
        acc[ 4] += p * v1.x; acc[ 5] += p * v1.y; acc[ 6] += p * v1.z; acc[ 7] += p * v1.w;
        acc[ 8] += p * v2.x; acc[ 9] += p * v2.y; acc[10] += p * v2.z; acc[11] += p * v2.w;
        acc[12] += p * v3.x; acc[13] += p * v3.y; acc[14] += p * v3.z; acc[15] += p * v3.w;
    }

    float inv = 1.0f / l;
    #pragma unroll
    for (int d = 0; d < 16; ++d)
        out[((size_t)bh * 16 + d) * HW + m] = acc[d] * inv;
}

// ---------------------------------------------------------------------------
extern "C" void kernel_launch(void* const* d_in, const int* in_sizes, int n_in,
                              void* d_out, int out_size, void* d_ws, size_t ws_size,
                              hipStream_t stream)
{
    const float* x        = (const float*)d_in[0];
    const float* wq       = (const float*)d_in[1];
    const float* bq       = (const float*)d_in[2];
    const float* off_dw_w = (const float*)d_in[3];
    const float* off_dw_b = (const float*)d_in[4];
    const float* ln_g     = (const float*)d_in[5];
    const float* ln_b     = (const float*)d_in[6];
    const float* off_pw_w = (const float*)d_in[7];
    const float* wk       = (const float*)d_in[8];
    const float* bk       = (const float*)d_in[9];
    const float* wv       = (const float*)d_in[10];
    const float* bv       = (const float*)d_in[11];
    const float* wo       = (const float*)d_in[12];
    const float* bo       = (const float*)d_in[13];
    const float* bn_g     = (const float*)d_in[14];
    const float* bn_b     = (const float*)d_in[15];
    const float* bn_m     = (const float*)d_in[16];
    const float* bn_v     = (const float*)d_in[17];

    float* ws  = (float*)d_ws;
    float* q   = ws;                       // 16*256*1024 = 4194304
    float* off = q   + 4194304;            // 16*256*256  = 1048576
    float* pos = off + 1048576;            // 16*256*2    = 8192
    float* xs  = pos + 8192;               // 1048576
    float* kb  = xs  + 1048576;            // 1048576
    float* vb  = kb  + 1048576;            // 1048576
    float* ao  = vb  + 1048576;            // 4194304

    conv1x1_k<HW, false><<<dim3(16, 4, BATCH), 256, 0, stream>>>(
        wq, x, bq, q, nullptr, nullptr, nullptr, nullptr);
    dwconv_k<<<BATCH * CH, 256, 0, stream>>>(q, off_dw_w, off_dw_b, off);
    lnoff_k<<<BATCH * NS, 256, 0, stream>>>(off, ln_g, ln_b, off_pw_w, pos);
    gsample_k<<<BATCH * NS, 256, 0, stream>>>(x, pos, xs);
    conv1x1_k<NS, false><<<dim3(4, 4, BATCH), 256, 0, stream>>>(
        wk, xs, bk, kb, nullptr, nullptr, nullptr, nullptr);
    conv1x1_k<NS, false><<<dim3(4, 4, BATCH), 256, 0, stream>>>(
        wv, xs, bv, vb, nullptr, nullptr, nullptr, nullptr);
    attn_k<<<BATCH * NH * 4, 256, 0, stream>>>(q, kb, vb, ao);
    conv1x1_k<HW, true><<<dim3(16, 4, BATCH), 256, 0, stream>>>(
        wo, ao, bo, (float*)d_out, bn_g, bn_b, bn_m, bn_v);
}

// Round 3
// 187.166 us; speedup vs baseline: 1.4760x; 1.3625x over previous
//
#include <hip/hip_runtime.h>
#include <hip/hip_bf16.h>
#include <math.h>

#define BATCH 16
#define CH    256
#define HDIM  32
#define WDIM  32
#define HW    1024
#define NS    256
#define NH    16
#define DH    16

typedef __attribute__((ext_vector_type(8))) short short8v;
typedef __attribute__((ext_vector_type(4))) float float4v;

__device__ __forceinline__ unsigned short f2bf(float f) {
    union { float f; unsigned u; } v; v.f = f;
    unsigned r = v.u + 0x7FFFu + ((v.u >> 16) & 1u);
    return (unsigned short)(r >> 16);
}

// ---------------------------------------------------------------------------
// conv1x1: Y[b,o,p] = sum_i W[o,i] * X[b,i,p] + bias[o]   (optional BN epilogue)
// ---------------------------------------------------------------------------
template<int P, bool BN>
__global__ __launch_bounds__(256) void conv1x1_k(
    const float* __restrict__ Wm, const float* __restrict__ X,
    const float* __restrict__ bias, float* __restrict__ Y,
    const float* __restrict__ bn_g, const float* __restrict__ bn_b,
    const float* __restrict__ bn_m, const float* __restrict__ bn_v)
{
    const int b  = blockIdx.z;
    const int o0 = blockIdx.y * 64;
    const int p0 = blockIdx.x * 64;
    __shared__ float Ws[16][64];   // [k][o]
    __shared__ float Xs[16][64];   // [k][p]
    const int t  = threadIdx.x;
    const int tr = t >> 4;
    const int tc = t & 15;
    float acc[4][4] = {};
    const float* Xb = X + (size_t)b * CH * P;

    for (int k0 = 0; k0 < CH; k0 += 16) {
        {
            int r = t >> 2;
            int c = (t & 3) << 2;
            float4 w4 = *(const float4*)&Wm[(size_t)(o0 + r) * CH + k0 + c];
            Ws[c + 0][r] = w4.x; Ws[c + 1][r] = w4.y;
            Ws[c + 2][r] = w4.z; Ws[c + 3][r] = w4.w;
        }
        {
            int r = t >> 4;
            int c = (t & 15) << 2;
            float4 x4 = *(const float4*)&Xb[(size_t)(k0 + r) * P + p0 + c];
            *(float4*)&Xs[r][c] = x4;
        }
        __syncthreads();
        #pragma unroll
        for (int kk = 0; kk < 16; ++kk) {
            float4 a4 = *(const float4*)&Ws[kk][tr * 4];
            float4 x4 = *(const float4*)&Xs[kk][tc * 4];
            acc[0][0] += a4.x * x4.x; acc[0][1] += a4.x * x4.y;
            acc[0][2] += a4.x * x4.z; acc[0][3] += a4.x * x4.w;
            acc[1][0] += a4.y * x4.x; acc[1][1] += a4.y * x4.y;
            acc[1][2] += a4.y * x4.z; acc[1][3] += a4.y * x4.w;
            acc[2][0] += a4.z * x4.x; acc[2][1] += a4.z * x4.y;
            acc[2][2] += a4.z * x4.z; acc[2][3] += a4.z * x4.w;
            acc[3][0] += a4.w * x4.x; acc[3][1] += a4.w * x4.y;
            acc[3][2] += a4.w * x4.z; acc[3][3] += a4.w * x4.w;
        }
        __syncthreads();
    }

    #pragma unroll
    for (int i = 0; i < 4; ++i) {
        int o = o0 + tr * 4 + i;
        float bs = bias[o];
        float scale = 1.0f, shift = 0.0f;
        if (BN) {
            float inv = rsqrtf(bn_v[o] + 1e-5f);
            scale = bn_g[o] * inv;
            shift = bn_b[o] - bn_m[o] * scale;
        }
        float4 r;
        r.x = acc[i][0] + bs; r.y = acc[i][1] + bs;
        r.z = acc[i][2] + bs; r.w = acc[i][3] + bs;
        if (BN) {
            r.x = r.x * scale + shift; r.y = r.y * scale + shift;
            r.z = r.z * scale + shift; r.w = r.w * scale + shift;
        }
        *(float4*)&Y[((size_t)b * CH + o) * P + p0 + tc * 4] = r;
    }
}

// ---------------------------------------------------------------------------
// depthwise 9x9 conv, stride 2, pad 4
// ---------------------------------------------------------------------------
__global__ __launch_bounds__(256) void dwconv_k(
    const float* __restrict__ q, const float* __restrict__ w,
    const float* __restrict__ bias, float* __restrict__ off)
{
    int bc = blockIdx.x;
    int c  = bc & (CH - 1);
    __shared__ float plane[HW];
    __shared__ float kw[81];
    int t = threadIdx.x;
    const float* qp = q + (size_t)bc * HW;
    #pragma unroll
    for (int j = t; j < HW; j += 256) plane[j] = qp[j];
    if (t < 81) kw[t] = w[c * 81 + t];
    __syncthreads();
    int hk = t >> 4, wk = t & 15;
    float s = bias[c];
    int yb = hk * 2 - 4, xb = wk * 2 - 4;
    #pragma unroll
    for (int dy = 0; dy < 9; ++dy) {
        int yy = yb + dy;
        if ((unsigned)yy < 32u) {
            #pragma unroll
            for (int dx = 0; dx < 9; ++dx) {
                int xx = xb + dx;
                if ((unsigned)xx < 32u) s += kw[dy * 9 + dx] * plane[yy * 32 + xx];
            }
        }
    }
    off[(size_t)bc * NS + t] = s;
}

// ---------------------------------------------------------------------------
// LN(channel) + GELU + projection + ref + tanh -> pos
// ---------------------------------------------------------------------------
__device__ inline void block_reduce2(float& a, float& b, int t, float* sbuf)
{
    #pragma unroll
    for (int o = 32; o > 0; o >>= 1) {
        a += __shfl_down(a, o);
        b += __shfl_down(b, o);
    }
    int w = t >> 6;
    if ((t & 63) == 0) { sbuf[w * 2] = a; sbuf[w * 2 + 1] = b; }
    __syncthreads();
    a = sbuf[0] + sbuf[2] + sbuf[4] + sbuf[6];
    b = sbuf[1] + sbuf[3] + sbuf[5] + sbuf[7];
    __syncthreads();
}

__global__ __launch_bounds__(256) void lnoff_k(
    const float* __restrict__ off, const float* __restrict__ ln_g,
    const float* __restrict__ ln_b, const float* __restrict__ pw,
    float* __restrict__ pos)
{
    __shared__ float sbuf[8];
    int bs = blockIdx.x;
    int b = bs >> 8, s = bs & 255;
    int c = threadIdx.x;
    float v = off[((size_t)(b * CH + c)) * NS + s];
    float a = v, q2 = v * v;
    block_reduce2(a, q2, c, sbuf);
    float mean = a * (1.0f / 256.0f);
    float var  = q2 * (1.0f / 256.0f) - mean * mean;
    float xn = (v - mean) * rsqrtf(var + 1e-5f) * ln_g[c] + ln_b[c];
    float g = 0.5f * xn * (1.0f + erff(xn * 0.70710678118654752f));
    float d0 = g * pw[c];
    float d1 = g * pw[CH + c];
    block_reduce2(d0, d1, c, sbuf);
    if (c == 0) {
        int hk = s >> 4, wk = s & 15;
        float ry = ((hk + 0.5f) / 16.0f) * 2.0f - 1.0f;
        float rx = ((wk + 0.5f) / 16.0f) * 2.0f - 1.0f;
        pos[bs * 2 + 0] = tanhf(d0 + ry);
        pos[bs * 2 + 1] = tanhf(d1 + rx);
    }
}

// ---------------------------------------------------------------------------
// bilinear grid sample
// ---------------------------------------------------------------------------
__global__ __launch_bounds__(256) void gsample_k(
    const float* __restrict__ x, const float* __restrict__ pos,
    float* __restrict__ xs)
{
    int bs = blockIdx.x;
    int b = bs >> 8, s = bs & 255;
    float py = pos[bs * 2 + 0];
    float px = pos[bs * 2 + 1];
    float gx = (px + 1.0f) * 0.5f * 31.0f;
    float gy = (py + 1.0f) * 0.5f * 31.0f;
    float x0f = floorf(gx), y0f = floorf(gy);
    int ix = (int)x0f, iy = (int)y0f;
    float wx1 = gx - x0f, wx0 = 1.0f - wx1;
    float wy1 = gy - y0f, wy0 = 1.0f - wy1;
    int c = threadIdx.x;
    const float* img = x + ((size_t)b * CH + c) * HW;
    float v00 = ((unsigned)iy < 32u && (unsigned)ix < 32u) ? img[iy * 32 + ix] : 0.0f;
    float v01 = ((unsigned)iy < 32u && (unsigned)(ix + 1) < 32u) ? img[iy * 32 + ix + 1] : 0.0f;
    float v10 = ((unsigned)(iy + 1) < 32u && (unsigned)ix < 32u) ? img[(iy + 1) * 32 + ix] : 0.0f;
    float v11 = ((unsigned)(iy + 1) < 32u && (unsigned)(ix + 1) < 32u) ? img[(iy + 1) * 32 + ix + 1] : 0.0f;
    float v = wy0 * wx0 * v00 + wy0 * wx1 * v01 + wy1 * wx0 * v10 + wy1 * wx1 * v11;
    xs[((size_t)b * CH + c) * NS + s] = v;
}

// ---------------------------------------------------------------------------
// MFMA attention. Swapped operands: S^T = K^T(16n x 32d) * Q^T(32d x 16m)
// via mfma_f32_16x16x32_bf16 (d zero-padded 16->32). Each lane then holds
// 64 of the 256 P-values of ONE query column; softmax = lane-local + 2 shfl.
// PV: O^T(16d x 16m) = V(16d x 32n) * P^T(32n x 16m), 8 chunks of K=32.
// Block = 4 waves, each wave 4 m-tiles; grid = BH * 4 (256 rows/block).
// ---------------------------------------------------------------------------
__global__ __launch_bounds__(256) void attn_mfma_k(
    const float* __restrict__ q, const float* __restrict__ K,
    const float* __restrict__ V, float* __restrict__ out)
{
    const int bh   = blockIdx.x >> 2;
    const int mseg = blockIdx.x & 3;

    __shared__ short Kp[16 * 64 * 8];   // 16KB: [t][lane][8 bf16]  A-frag layout
    __shared__ short Vsh[16 * 256];     // 8KB:  [d][n] bf16, byte ^= (d&7)<<4
    __shared__ short Ps[4][16 * 32];    // 1KB/wave P chunk scratch, byte ^= (m&7)<<4

    const int tid  = threadIdx.x;
    const int lane = tid & 63;
    const int wv   = tid >> 6;
    const int col  = lane & 15;
    const int g    = lane >> 4;

    // ---- stage K: Kp[t][l] = { K[8*(l>>4)+i][16t + (l&15)] } for l<32, zeros l>=32
    const float* Kb = K + (size_t)bh * DH * NS;
    for (int e = tid; e < 512; e += 256) {
        int t = e >> 5, l = e & 31, gg = l >> 4, c = l & 15;
        short8v kk;
        #pragma unroll
        for (int i = 0; i < 8; ++i)
            kk[i] = (short)f2bf(Kb[(8 * gg + i) * NS + 16 * t + c]);
        *(short8v*)&Kp[(t * 64 + l) * 8] = kk;
        short8v z = {0,0,0,0,0,0,0,0};
        *(short8v*)&Kp[(t * 64 + 32 + l) * 8] = z;
    }
    // ---- stage V bf16 with XOR-swizzled rows
    {
        const float* Vb = V + (size_t)bh * DH * NS;
        int d = tid >> 4, n0 = (tid & 15) * 16;
        char* vb = (char*)Vsh;
        #pragma unroll
        for (int h = 0; h < 2; ++h) {
            short8v pk;
            #pragma unroll
            for (int i = 0; i < 8; ++i)
                pk[i] = (short)f2bf(Vb[d * NS + n0 + 8 * h + i]);
            *(short8v*)(vb + ((d * 512 + (n0 + 8 * h) * 2) ^ ((d & 7) << 4))) = pk;
        }
    }
    __syncthreads();

    const float* Qb = q + (size_t)bh * DH * HW;
    float*       Ob = out + (size_t)bh * DH * HW;
    char* pbase = (char*)Ps[wv];
    char* vbase = (char*)Vsh;

    for (int mt = 0; mt < 4; ++mt) {
        const int m0 = mseg * 256 + wv * 64 + mt * 16;

        // Q B-frag: col m = lane&15, k(d) = 8g+i (zeros for g>=2)
        short8v qf = {0,0,0,0,0,0,0,0};
        if (g < 2) {
            #pragma unroll
            for (int i = 0; i < 8; ++i)
                qf[i] = (short)f2bf(Qb[(8 * g + i) * HW + m0 + col] * 0.25f);
        }

        // QK^T: 16 n-tiles
        float4v p[16];
        #pragma unroll
        for (int t = 0; t < 16; ++t) {
            short8v kf = *(const short8v*)&Kp[(t * 64 + lane) * 8];
            float4v z = {0.f, 0.f, 0.f, 0.f};
            p[t] = __builtin_amdgcn_mfma_f32_16x16x32_bf16(kf, qf, z, 0, 0, 0);
        }

        // softmax over n (lane holds col m, rows n = 16t + 4g + i)
        float mx = -1e30f;
        #pragma unroll
        for (int t = 0; t < 16; ++t)
            mx = fmaxf(mx, fmaxf(fmaxf(p[t][0], p[t][1]), fmaxf(p[t][2], p[t][3])));
        mx = fmaxf(mx, __shfl_xor(mx, 16));
        mx = fmaxf(mx, __shfl_xor(mx, 32));
        float sum = 0.f;
        #pragma unroll
        for (int t = 0; t < 16; ++t) {
            #pragma unroll
            for (int i = 0; i < 4; ++i) {
                float e = __expf(p[t][i] - mx);
                p[t][i] = e;
                sum += e;
            }
        }
        sum += __shfl_xor(sum, 16);
        sum += __shfl_xor(sum, 32);
        const float inv = 1.0f / sum;

        // PV: 8 chunks of 32 n
        float4v acc = {0.f, 0.f, 0.f, 0.f};
        #pragma unroll
        for (int c = 0; c < 8; ++c) {
            #pragma unroll
            for (int pp = 0; pp < 2; ++pp) {
                float4v pv = p[2 * c + pp];
                uint2 wr;
                wr.x = (unsigned)f2bf(pv[0]) | ((unsigned)f2bf(pv[1]) << 16);
                wr.y = (unsigned)f2bf(pv[2]) | ((unsigned)f2bf(pv[3]) << 16);
                *(uint2*)(pbase + ((col * 64 + (16 * pp + 4 * g) * 2) ^ ((col & 7) << 4))) = wr;
            }
            short8v pf = *(const short8v*)(pbase + ((col * 64 + 16 * g) ^ ((col & 7) << 4)));
            short8v vf = *(const short8v*)(vbase + ((col * 512 + 64 * c + 16 * g) ^ ((col & 7) << 4)));
            acc = __builtin_amdgcn_mfma_f32_16x16x32_bf16(vf, pf, acc, 0, 0, 0);
        }

        // epilogue: Ot col m = lane&15, rows d = 4g+i
        #pragma unroll
        for (int i = 0; i < 4; ++i)
            Ob[(4 * g + i) * HW + m0 + col] = acc[i] * inv;
    }
}

// ---------------------------------------------------------------------------
extern "C" void kernel_launch(void* const* d_in, const int* in_sizes, int n_in,
                              void* d_out, int out_size, void* d_ws, size_t ws_size,
                              hipStream_t stream)
{
    const float* x        = (const float*)d_in[0];
    const float* wq       = (const float*)d_in[1];
    const float* bq       = (const float*)d_in[2];
    const float* off_dw_w = (const float*)d_in[3];
    const float* off_dw_b = (const float*)d_in[4];
    const float* ln_g     = (const float*)d_in[5];
    const float* ln_b     = (const float*)d_in[6];
    const float* off_pw_w = (const float*)d_in[7];
    const float* wk       = (const float*)d_in[8];
    const float* bk       = (const float*)d_in[9];
    const float* wv       = (const float*)d_in[10];
    const float* bv       = (const float*)d_in[11];
    const float* wo       = (const float*)d_in[12];
    const float* bo       = (const float*)d_in[13];
    const float* bn_g     = (const float*)d_in[14];
    const float* bn_b     = (const float*)d_in[15];
    const float* bn_m     = (const float*)d_in[16];
    const float* bn_v     = (const float*)d_in[17];

    float* ws  = (float*)d_ws;
    float* q   = ws;                       // 4194304
    float* off = q   + 4194304;            // 1048576
    float* pos = off + 1048576;            // 8192
    float* xs  = pos + 8192;               // 1048576
    float* kb  = xs  + 1048576;            // 1048576
    float* vb  = kb  + 1048576;            // 1048576
    float* ao  = vb  + 1048576;            // 4194304

    conv1x1_k<HW, false><<<dim3(16, 4, BATCH), 256, 0, stream>>>(
        wq, x, bq, q, nullptr, nullptr, nullptr, nullptr);
    dwconv_k<<<BATCH * CH, 256, 0, stream>>>(q, off_dw_w, off_dw_b, off);
    lnoff_k<<<BATCH * NS, 256, 0, stream>>>(off, ln_g, ln_b, off_pw_w, pos);
    gsample_k<<<BATCH * NS, 256, 0, stream>>>(x, pos, xs);
    conv1x1_k<NS, false><<<dim3(4, 4, BATCH), 256, 0, stream>>>(
        wk, xs, bk, kb, nullptr, nullptr, nullptr, nullptr);
    conv1x1_k<NS, false><<<dim3(4, 4, BATCH), 256, 0, stream>>>(
        wv, xs, bv, vb, nullptr, nullptr, nullptr, nullptr);
    attn_mfma_k<<<BATCH * NH * 4, 256, 0, stream>>>(q, kb, vb, ao);
    conv1x1_k<HW, true><<<dim3(16, 4, BATCH), 256, 0, stream>>>(
        wo, ao, bo, (float*)d_out, bn_g, bn_b, bn_m, bn_v);
}

// Round 4
// 139.762 us; speedup vs baseline: 1.9766x; 1.3392x over previous
//
#include <hip/hip_runtime.h>
#include <hip/hip_bf16.h>
#include <math.h>

#define BATCH 16
#define CH    256
#define HW    1024
#define NS    256
#define NH    16
#define DH    16

typedef __attribute__((ext_vector_type(8))) short short8v;
typedef __attribute__((ext_vector_type(4))) float float4v;

__device__ __forceinline__ unsigned short f2bf(float f) {
    union { float f; unsigned u; } v; v.f = f;
    unsigned r = v.u + 0x7FFFu + ((v.u >> 16) & 1u);
    return (unsigned short)(r >> 16);
}

// ---------------------------------------------------------------------------
// weight prep: W[256][256] fp32 -> bf16 in MFMA A-fragment order:
// Wf[((ot*8+kt)*64+l)*8+i] = W[ot*16+(l&15)][kt*32+8*(l>>4)+i]
// ---------------------------------------------------------------------------
__global__ __launch_bounds__(256) void wprep_k(
    const float* __restrict__ wq, const float* __restrict__ wk,
    const float* __restrict__ wv, const float* __restrict__ wo,
    unsigned short* __restrict__ Wf)
{
    const float* W;
    switch (blockIdx.y) {
        case 0: W = wq; break;
        case 1: W = wk; break;
        case 2: W = wv; break;
        default: W = wo; break;
    }
    int e = blockIdx.x * 256 + threadIdx.x;      // 0..65535
    int i = e & 7, l = (e >> 3) & 63, kt = (e >> 9) & 7, ot = e >> 12;
    float v = W[(ot * 16 + (l & 15)) * 256 + kt * 32 + 8 * (l >> 4) + i];
    Wf[blockIdx.y * 65536 + e] = f2bf(v);
}

// ---------------------------------------------------------------------------
// x[b][c][p] fp32 -> xT[b][p][c] bf16 (coalesced reads along p, b128 writes)
// ---------------------------------------------------------------------------
__global__ __launch_bounds__(256) void xt_k(
    const float* __restrict__ x, unsigned short* __restrict__ xT)
{
    int b = blockIdx.y;
    int p = blockIdx.x * 256 + threadIdx.x;
    const float* xb = x + (size_t)b * CH * HW + p;
    unsigned short* o = xT + ((size_t)b * HW + p) * CH;
    for (int c0 = 0; c0 < CH; c0 += 8) {
        short8v t;
        #pragma unroll
        for (int i = 0; i < 8; ++i) t[i] = (short)f2bf(xb[(size_t)(c0 + i) * HW]);
        *(short8v*)&o[c0] = t;
    }
}

// ---------------------------------------------------------------------------
// bf16 MFMA GEMM conv1x1: C[o][p] = W[o][:] . X[:][p]  (K=256)
// block: 256 thr / 4 waves; tile 64(M) x 128(N); wave = 64x32; no LDS.
// MODE 0: Q   -> outF fp32 [b][o][p]  +  outB bf16 qT [b][p][o]
// MODE 1: KV  -> blockIdx.z>>4 picks mat: 0: kT bf16 [b][p][o]; 1: v bf16 [b][o][p]
// MODE 2: O   -> outF fp32 d_out with BN epilogue
// ---------------------------------------------------------------------------
template<int P, int MODE>
__global__ __launch_bounds__(256) void gemm_k(
    const unsigned short* __restrict__ Wf, const unsigned short* __restrict__ XT,
    const float* __restrict__ bias, const float* __restrict__ bias2,
    float* __restrict__ outF, unsigned short* __restrict__ outB,
    unsigned short* __restrict__ outB2,
    const float* __restrict__ bn_g, const float* __restrict__ bn_b,
    const float* __restrict__ bn_m, const float* __restrict__ bn_v)
{
    const int bz  = blockIdx.z;
    const int b   = (MODE == 1) ? (bz & 15) : bz;
    const int mat = (MODE == 1) ? (bz >> 4) : 0;
    const unsigned short* Wfm = Wf + mat * 65536;

    const int t = threadIdx.x, lane = t & 63, wvi = t >> 6;
    const int g = lane >> 4, col = lane & 15;
    const int o0 = blockIdx.x * 64;
    const int p0 = blockIdx.y * 128 + wvi * 32;
    const unsigned short* xb = XT + ((size_t)b * P + p0) * CH;

    float4v acc[4][2];
    #pragma unroll
    for (int mi = 0; mi < 4; ++mi)
        #pragma unroll
        for (int ni = 0; ni < 2; ++ni) {
            float4v z = {0.f, 0.f, 0.f, 0.f};
            acc[mi][ni] = z;
        }

    #pragma unroll
    for (int kt = 0; kt < 8; ++kt) {
        short8v af[4], bf[2];
        #pragma unroll
        for (int mi = 0; mi < 4; ++mi)
            af[mi] = *(const short8v*)&Wfm[(((((o0 >> 4) + mi) * 8) + kt) * 64 + lane) * 8];
        #pragma unroll
        for (int ni = 0; ni < 2; ++ni)
            bf[ni] = *(const short8v*)&xb[(size_t)(ni * 16 + col) * CH + kt * 32 + 8 * g];
        #pragma unroll
        for (int mi = 0; mi < 4; ++mi)
            #pragma unroll
            for (int ni = 0; ni < 2; ++ni)
                acc[mi][ni] = __builtin_amdgcn_mfma_f32_16x16x32_bf16(
                    af[mi], bf[ni], acc[mi][ni], 0, 0, 0);
    }

    const float* bp = (MODE == 1 && mat == 1) ? bias2 : bias;
    #pragma unroll
    for (int mi = 0; mi < 4; ++mi) {
        const int ob = o0 + mi * 16 + 4 * g;
        float bs[4];
        #pragma unroll
        for (int ii = 0; ii < 4; ++ii) bs[ii] = bp[ob + ii];

        if (MODE == 2) {
            float sc[4], sh[4];
            #pragma unroll
            for (int ii = 0; ii < 4; ++ii) {
                int o = ob + ii;
                float s = bn_g[o] * rsqrtf(bn_v[o] + 1e-5f);
                sc[ii] = s;
                sh[ii] = bn_b[o] - bn_m[o] * s + bs[ii] * s;
            }
            #pragma unroll
            for (int ni = 0; ni < 2; ++ni) {
                int p = p0 + ni * 16 + col;
                #pragma unroll
                for (int ii = 0; ii < 4; ++ii)
                    outF[((size_t)(b * CH + ob + ii)) * P + p] =
                        acc[mi][ni][ii] * sc[ii] + sh[ii];
            }
        } else {
            #pragma unroll
            for (int ni = 0; ni < 2; ++ni) {
                int p = p0 + ni * 16 + col;
                float v0 = acc[mi][ni][0] + bs[0];
                float v1 = acc[mi][ni][1] + bs[1];
                float v2 = acc[mi][ni][2] + bs[2];
                float v3 = acc[mi][ni][3] + bs[3];
                if (MODE == 0) {
                    outF[((size_t)(b * CH + ob + 0)) * P + p] = v0;
                    outF[((size_t)(b * CH + ob + 1)) * P + p] = v1;
                    outF[((size_t)(b * CH + ob + 2)) * P + p] = v2;
                    outF[((size_t)(b * CH + ob + 3)) * P + p] = v3;
                    uint2 w;
                    w.x = (unsigned)f2bf(v0) | ((unsigned)f2bf(v1) << 16);
                    w.y = (unsigned)f2bf(v2) | ((unsigned)f2bf(v3) << 16);
                    *(uint2*)&outB[((size_t)(b * P + p)) * CH + ob] = w;
                } else { // MODE 1
                    if (mat == 0) {
                        uint2 w;
                        w.x = (unsigned)f2bf(v0) | ((unsigned)f2bf(v1) << 16);
                        w.y = (unsigned)f2bf(v2) | ((unsigned)f2bf(v3) << 16);
                        *(uint2*)&outB[((size_t)(b * P + p)) * CH + ob] = w;
                    } else {
                        outB2[((size_t)(b * CH + ob + 0)) * P + p] = f2bf(v0);
                        outB2[((size_t)(b * CH + ob + 1)) * P + p] = f2bf(v1);
                        outB2[((size_t)(b * CH + ob + 2)) * P + p] = f2bf(v2);
                        outB2[((size_t)(b * CH + ob + 3)) * P + p] = f2bf(v3);
                    }
                }
            }
        }
    }
}

// ---------------------------------------------------------------------------
// depthwise 9x9 conv, stride 2, pad 4 (q fp32 [b][c][32][32] -> off [b][c][16][16])
// ---------------------------------------------------------------------------
__global__ __launch_bounds__(256) void dwconv_k(
    const float* __restrict__ q, const float* __restrict__ w,
    const float* __restrict__ bias, float* __restrict__ off)
{
    int bc = blockIdx.x;
    int c  = bc & (CH - 1);
    __shared__ float plane[HW];
    __shared__ float kw[81];
    int t = threadIdx.x;
    const float* qp = q + (size_t)bc * HW;
    #pragma unroll
    for (int j = t; j < HW; j += 256) plane[j] = qp[j];
    if (t < 81) kw[t] = w[c * 81 + t];
    __syncthreads();
    int hk = t >> 4, wk = t & 15;
    float s = bias[c];
    int yb = hk * 2 - 4, xb = wk * 2 - 4;
    #pragma unroll
    for (int dy = 0; dy < 9; ++dy) {
        int yy = yb + dy;
        if ((unsigned)yy < 32u) {
            #pragma unroll
            for (int dx = 0; dx < 9; ++dx) {
                int xx = xb + dx;
                if ((unsigned)xx < 32u) s += kw[dy * 9 + dx] * plane[yy * 32 + xx];
            }
        }
    }
    off[(size_t)bc * NS + t] = s;
}

// ---------------------------------------------------------------------------
// LN(channel) + GELU + projection + ref + tanh -> pos
// ---------------------------------------------------------------------------
__device__ inline void block_reduce2(float& a, float& b, int t, float* sbuf)
{
    #pragma unroll
    for (int o = 32; o > 0; o >>= 1) {
        a += __shfl_down(a, o);
        b += __shfl_down(b, o);
    }
    int w = t >> 6;
    if ((t & 63) == 0) { sbuf[w * 2] = a; sbuf[w * 2 + 1] = b; }
    __syncthreads();
    a = sbuf[0] + sbuf[2] + sbuf[4] + sbuf[6];
    b = sbuf[1] + sbuf[3] + sbuf[5] + sbuf[7];
    __syncthreads();
}

__global__ __launch_bounds__(256) void lnoff_k(
    const float* __restrict__ off, const float* __restrict__ ln_g,
    const float* __restrict__ ln_b, const float* __restrict__ pw,
    float* __restrict__ pos)
{
    __shared__ float sbuf[8];
    int bs = blockIdx.x;
    int b = bs >> 8, s = bs & 255;
    int c = threadIdx.x;
    float v = off[((size_t)(b * CH + c)) * NS + s];
    float a = v, q2 = v * v;
    block_reduce2(a, q2, c, sbuf);
    float mean = a * (1.0f / 256.0f);
    float var  = q2 * (1.0f / 256.0f) - mean * mean;
    float xn = (v - mean) * rsqrtf(var + 1e-5f) * ln_g[c] + ln_b[c];
    float g = 0.5f * xn * (1.0f + erff(xn * 0.70710678118654752f));
    float d0 = g * pw[c];
    float d1 = g * pw[CH + c];
    block_reduce2(d0, d1, c, sbuf);
    if (c == 0) {
        int hk = s >> 4, wk = s & 15;
        float ry = ((hk + 0.5f) / 16.0f) * 2.0f - 1.0f;
        float rx = ((wk + 0.5f) / 16.0f) * 2.0f - 1.0f;
        pos[bs * 2 + 0] = tanhf(d0 + ry);
        pos[bs * 2 + 1] = tanhf(d1 + rx);
    }
}

// ---------------------------------------------------------------------------
// bilinear grid sample -> xsT bf16 [b][s][c] (coalesced, K-contiguous for GEMM)
// ---------------------------------------------------------------------------
__global__ __launch_bounds__(256) void gsample_k(
    const float* __restrict__ x, const float* __restrict__ pos,
    unsigned short* __restrict__ xsT)
{
    int bs = blockIdx.x;
    int b = bs >> 8;
    float py = pos[bs * 2 + 0];
    float px = pos[bs * 2 + 1];
    float gx = (px + 1.0f) * 0.5f * 31.0f;
    float gy = (py + 1.0f) * 0.5f * 31.0f;
    float x0f = floorf(gx), y0f = floorf(gy);
    int ix = (int)x0f, iy = (int)y0f;
    float wx1 = gx - x0f, wx0 = 1.0f - wx1;
    float wy1 = gy - y0f, wy0 = 1.0f - wy1;
    int c = threadIdx.x;
    const float* img = x + ((size_t)b * CH + c) * HW;
    float v00 = ((unsigned)iy < 32u && (unsigned)ix < 32u) ? img[iy * 32 + ix] : 0.0f;
    float v01 = ((unsigned)iy < 32u && (unsigned)(ix + 1) < 32u) ? img[iy * 32 + ix + 1] : 0.0f;
    float v10 = ((unsigned)(iy + 1) < 32u && (unsigned)ix < 32u) ? img[(iy + 1) * 32 + ix] : 0.0f;
    float v11 = ((unsigned)(iy + 1) < 32u && (unsigned)(ix + 1) < 32u) ? img[(iy + 1) * 32 + ix + 1] : 0.0f;
    float v = wy0 * wx0 * v00 + wy0 * wx1 * v01 + wy1 * wx0 * v10 + wy1 * wx1 * v11;
    xsT[(size_t)bs * CH + c] = f2bf(v);
}

// ---------------------------------------------------------------------------
// MFMA attention (all-bf16 I/O). qT[b][m][c], kT[b][n][c], v[b][c][n] -> aoT[b][m][c]
// S^T = K^T * Q^T (d zero-padded 16->32); softmax lane-local (0.25 folded in);
// PV: O^T = V * P^T in 8 K=32 chunks.
// ---------------------------------------------------------------------------
__global__ __launch_bounds__(256) void attn_mfma_k(
    const unsigned short* __restrict__ qT, const unsigned short* __restrict__ kT,
    const unsigned short* __restrict__ vbf, unsigned short* __restrict__ aoT)
{
    const int bh   = blockIdx.x >> 2;
    const int mseg = blockIdx.x & 3;
    const int b = bh >> 4, h = bh & 15;

    __shared__ short Kp[16 * 64 * 8];   // A-frag order
    __shared__ short Vsh[16 * 256];     // [d][n], byte ^= (d&7)<<4
    __shared__ short Ps[4][16 * 32];    // per-wave P scratch, byte ^= (m&7)<<4

    const int tid  = threadIdx.x;
    const int lane = tid & 63;
    const int wvi  = tid >> 6;
    const int col  = lane & 15;
    const int g    = lane >> 4;

    for (int e = tid; e < 512; e += 256) {
        int t = e >> 5, l = e & 31, gg = l >> 4, c = l & 15;
        short8v kk = *(const short8v*)&kT[((size_t)(b * NS + 16 * t + c)) * CH + h * 16 + 8 * gg];
        *(short8v*)&Kp[(t * 64 + l) * 8] = kk;
        short8v z = {0, 0, 0, 0, 0, 0, 0, 0};
        *(short8v*)&Kp[(t * 64 + 32 + l) * 8] = z;
    }
    {
        const unsigned short* Vb = vbf + ((size_t)(b * CH + h * 16)) * NS;
        int d = tid >> 4, n0 = (tid & 15) * 16;
        char* vb = (char*)Vsh;
        #pragma unroll
        for (int hh = 0; hh < 2; ++hh) {
            short8v pk = *(const short8v*)&Vb[(size_t)d * NS + n0 + 8 * hh];
            *(short8v*)(vb + ((d * 512 + (n0 + 8 * hh) * 2) ^ ((d & 7) << 4))) = pk;
        }
    }
    __syncthreads();

    const unsigned short* Qb = qT + (size_t)b * HW * CH + h * 16;
    unsigned short*       Ob = aoT + (size_t)b * HW * CH + h * 16;
    char* pbase = (char*)Ps[wvi];
    char* vbase = (char*)Vsh;

    for (int mt = 0; mt < 4; ++mt) {
        const int m0 = mseg * 256 + wvi * 64 + mt * 16;

        short8v qf = {0, 0, 0, 0, 0, 0, 0, 0};
        if (g < 2)
            qf = *(const short8v*)&Qb[(size_t)(m0 + col) * CH + 8 * g];

        float4v p[16];
        #pragma unroll
        for (int t = 0; t < 16; ++t) {
            short8v kf = *(const short8v*)&Kp[(t * 64 + lane) * 8];
            float4v z = {0.f, 0.f, 0.f, 0.f};
            p[t] = __builtin_amdgcn_mfma_f32_16x16x32_bf16(kf, qf, z, 0, 0, 0);
        }

        float mx = -1e30f;
        #pragma unroll
        for (int t = 0; t < 16; ++t)
            mx = fmaxf(mx, fmaxf(fmaxf(p[t][0], p[t][1]), fmaxf(p[t][2], p[t][3])));
        mx = fmaxf(mx, __shfl_xor(mx, 16));
        mx = fmaxf(mx, __shfl_xor(mx, 32));
        float sum = 0.f;
        #pragma unroll
        for (int t = 0; t < 16; ++t) {
            #pragma unroll
            for (int i = 0; i < 4; ++i) {
                float e = __expf((p[t][i] - mx) * 0.25f);
                p[t][i] = e;
                sum += e;
            }
        }
        sum += __shfl_xor(sum, 16);
        sum += __shfl_xor(sum, 32);
        const float inv = 1.0f / sum;

        float4v acc = {0.f, 0.f, 0.f, 0.f};
        #pragma unroll
        for (int c = 0; c < 8; ++c) {
            #pragma unroll
            for (int pp = 0; pp < 2; ++pp) {
                float4v pv = p[2 * c + pp];
                uint2 wr;
                wr.x = (unsigned)f2bf(pv[0]) | ((unsigned)f2bf(pv[1]) << 16);
                wr.y = (unsigned)f2bf(pv[2]) | ((unsigned)f2bf(pv[3]) << 16);
                *(uint2*)(pbase + ((col * 64 + (16 * pp + 4 * g) * 2) ^ ((col & 7) << 4))) = wr;
            }
            short8v pf = *(const short8v*)(pbase + ((col * 64 + 16 * g) ^ ((col & 7) << 4)));
            short8v vf = *(const short8v*)(vbase + ((col * 512 + 64 * c + 16 * g) ^ ((col & 7) << 4)));
            acc = __builtin_amdgcn_mfma_f32_16x16x32_bf16(vf, pf, acc, 0, 0, 0);
        }

        uint2 w;
        w.x = (unsigned)f2bf(acc[0] * inv) | ((unsigned)f2bf(acc[1] * inv) << 16);
        w.y = (unsigned)f2bf(acc[2] * inv) | ((unsigned)f2bf(acc[3] * inv) << 16);
        *(uint2*)&Ob[(size_t)(m0 + col) * CH + 4 * g] = w;
    }
}

// ---------------------------------------------------------------------------
extern "C" void kernel_launch(void* const* d_in, const int* in_sizes, int n_in,
                              void* d_out, int out_size, void* d_ws, size_t ws_size,
                              hipStream_t stream)
{
    const float* x        = (const float*)d_in[0];
    const float* wq       = (const float*)d_in[1];
    const float* bq       = (const float*)d_in[2];
    const float* off_dw_w = (const float*)d_in[3];
    const float* off_dw_b = (const float*)d_in[4];
    const float* ln_g     = (const float*)d_in[5];
    const float* ln_b     = (const float*)d_in[6];
    const float* off_pw_w = (const float*)d_in[7];
    const float* wk       = (const float*)d_in[8];
    const float* bk       = (const float*)d_in[9];
    const float* wv       = (const float*)d_in[10];
    const float* bv       = (const float*)d_in[11];
    const float* wo       = (const float*)d_in[12];
    const float* bo       = (const float*)d_in[13];
    const float* bn_g     = (const float*)d_in[14];
    const float* bn_b     = (const float*)d_in[15];
    const float* bn_m     = (const float*)d_in[16];
    const float* bn_v     = (const float*)d_in[17];

    float* ws  = (float*)d_ws;
    float* q   = ws;                        // 4194304 f (q fp32 for dwconv)
    float* off = q + 4194304;               // 1048576 f
    float* pos = off + 1048576;             // 8192 f
    unsigned short* us  = (unsigned short*)(pos + 8192);
    unsigned short* Wf  = us;               //  262144 us (4 frag-packed weights)
    unsigned short* xT  = Wf  + 262144;     // 4194304 us
    unsigned short* qT  = xT  + 4194304;    // 4194304 us
    unsigned short* xsT = qT  + 4194304;    // 1048576 us
    unsigned short* kT  = xsT + 1048576;    // 1048576 us
    unsigned short* vbf = kT  + 1048576;    // 1048576 us
    unsigned short* aoT = vbf + 1048576;    // 4194304 us

    wprep_k<<<dim3(256, 4), 256, 0, stream>>>(wq, wk, wv, wo, Wf);
    xt_k<<<dim3(4, 16), 256, 0, stream>>>(x, xT);
    gemm_k<HW, 0><<<dim3(4, 8, BATCH), 256, 0, stream>>>(
        Wf, xT, bq, nullptr, q, qT, nullptr, nullptr, nullptr, nullptr, nullptr);
    dwconv_k<<<BATCH * CH, 256, 0, stream>>>(q, off_dw_w, off_dw_b, off);
    lnoff_k<<<BATCH * NS, 256, 0, stream>>>(off, ln_g, ln_b, off_pw_w, pos);
    gsample_k<<<BATCH * NS, 256, 0, stream>>>(x, pos, xsT);
    gemm_k<NS, 1><<<dim3(4, 2, 2 * BATCH), 256, 0, stream>>>(
        Wf + 65536, xsT, bk, bv, nullptr, kT, vbf, nullptr, nullptr, nullptr, nullptr);
    attn_mfma_k<<<BATCH * NH * 4, 256, 0, stream>>>(qT, kT, vbf, aoT);
    gemm_k<HW, 2><<<dim3(4, 8, BATCH), 256, 0, stream>>>(
        Wf + 3 * 65536, aoT, bo, nullptr, (float*)d_out, nullptr, nullptr,
        bn_g, bn_b, bn_m, bn_v);
}

// Round 5
// 119.791 us; speedup vs baseline: 2.3062x; 1.1667x over previous
//
#include <hip/hip_runtime.h>
#include <hip/hip_bf16.h>
#include <math.h>

#define BATCH 16
#define CH    256
#define HW    1024
#define NS    256
#define NH    16
#define DH    16

typedef __attribute__((ext_vector_type(8))) short short8v;
typedef __attribute__((ext_vector_type(4))) float float4v;

__device__ __forceinline__ unsigned short f2bf(float f) {
    union { float f; unsigned u; } v; v.f = f;
    unsigned r = v.u + 0x7FFFu + ((v.u >> 16) & 1u);
    return (unsigned short)(r >> 16);
}

// ---------------------------------------------------------------------------
// prep: blocks 0..1023  -> weight repack (4 matrices, A-frag order)
//       blocks 1024..1279 -> x[b][c][p] fp32 -> xT[b][p][c] bf16
// Wf[((ot*8+kt)*64+l)*8+i] = W[ot*16+(l&15)][kt*32+8*(l>>4)+i]
// ---------------------------------------------------------------------------
__global__ __launch_bounds__(256) void prep_k(
    const float* __restrict__ wq, const float* __restrict__ wk,
    const float* __restrict__ wv, const float* __restrict__ wo,
    unsigned short* __restrict__ Wf,
    const float* __restrict__ x, unsigned short* __restrict__ xT)
{
    int blk = blockIdx.x;
    if (blk < 1024) {
        const float* W;
        switch (blk >> 8) {
            case 0: W = wq; break;
            case 1: W = wk; break;
            case 2: W = wv; break;
            default: W = wo; break;
        }
        int e = (blk & 255) * 256 + threadIdx.x;     // 0..65535
        int i = e & 7, l = (e >> 3) & 63, kt = (e >> 9) & 7, ot = e >> 12;
        float v = W[(ot * 16 + (l & 15)) * 256 + kt * 32 + 8 * (l >> 4) + i];
        Wf[(blk >> 8) * 65536 + e] = f2bf(v);
    } else {
        int xb = blk - 1024;                          // 0..255
        int b = xb >> 4, pblk = (xb >> 2) & 3, cblk = xb & 3;
        int p = pblk * 256 + threadIdx.x;
        const float* xp = x + (size_t)b * CH * HW + p;
        unsigned short* o = xT + ((size_t)b * HW + p) * CH;
        #pragma unroll
        for (int cc = 0; cc < 64; cc += 8) {
            int c0 = cblk * 64 + cc;
            short8v t;
            #pragma unroll
            for (int i = 0; i < 8; ++i) t[i] = (short)f2bf(xp[(size_t)(c0 + i) * HW]);
            *(short8v*)&o[c0] = t;
        }
    }
}

// ---------------------------------------------------------------------------
// bf16 MFMA GEMM conv1x1: C[o][p] = W[o][:] . X[:][p]  (K=256)
// block: 256 thr / 4 waves; tile 64(M) x 128(N); wave = 64x32; no LDS.
// MODE 0: Q   -> outF fp32 [b][o][p]  +  outB bf16 qT [b][p][o]
// MODE 1: KV  -> blockIdx.z>>4 picks mat: 0: kT bf16 [b][p][o]; 1: v bf16 [b][o][p]
// MODE 2: O   -> outF fp32 d_out with BN epilogue
// ---------------------------------------------------------------------------
template<int P, int MODE>
__global__ __launch_bounds__(256) void gemm_k(
    const unsigned short* __restrict__ Wf, const unsigned short* __restrict__ XT,
    const float* __restrict__ bias, const float* __restrict__ bias2,
    float* __restrict__ outF, unsigned short* __restrict__ outB,
    unsigned short* __restrict__ outB2,
    const float* __restrict__ bn_g, const float* __restrict__ bn_b,
    const float* __restrict__ bn_m, const float* __restrict__ bn_v)
{
    const int bz  = blockIdx.z;
    const int b   = (MODE == 1) ? (bz & 15) : bz;
    const int mat = (MODE == 1) ? (bz >> 4) : 0;
    const unsigned short* Wfm = Wf + mat * 65536;

    const int t = threadIdx.x, lane = t & 63, wvi = t >> 6;
    const int g = lane >> 4, col = lane & 15;
    const int o0 = blockIdx.x * 64;
    const int p0 = blockIdx.y * 128 + wvi * 32;
    const unsigned short* xb = XT + ((size_t)b * P + p0) * CH;

    float4v acc[4][2];
    #pragma unroll
    for (int mi = 0; mi < 4; ++mi)
        #pragma unroll
        for (int ni = 0; ni < 2; ++ni) {
            float4v z = {0.f, 0.f, 0.f, 0.f};
            acc[mi][ni] = z;
        }

    #pragma unroll
    for (int kt = 0; kt < 8; ++kt) {
        short8v af[4], bf[2];
        #pragma unroll
        for (int mi = 0; mi < 4; ++mi)
            af[mi] = *(const short8v*)&Wfm[(((((o0 >> 4) + mi) * 8) + kt) * 64 + lane) * 8];
        #pragma unroll
        for (int ni = 0; ni < 2; ++ni)
            bf[ni] = *(const short8v*)&xb[(size_t)(ni * 16 + col) * CH + kt * 32 + 8 * g];
        #pragma unroll
        for (int mi = 0; mi < 4; ++mi)
            #pragma unroll
            for (int ni = 0; ni < 2; ++ni)
                acc[mi][ni] = __builtin_amdgcn_mfma_f32_16x16x32_bf16(
                    af[mi], bf[ni], acc[mi][ni], 0, 0, 0);
    }

    const float* bp = (MODE == 1 && mat == 1) ? bias2 : bias;
    #pragma unroll
    for (int mi = 0; mi < 4; ++mi) {
        const int ob = o0 + mi * 16 + 4 * g;
        float bs[4];
        #pragma unroll
        for (int ii = 0; ii < 4; ++ii) bs[ii] = bp[ob + ii];

        if (MODE == 2) {
            float sc[4], sh[4];
            #pragma unroll
            for (int ii = 0; ii < 4; ++ii) {
                int o = ob + ii;
                float s = bn_g[o] * rsqrtf(bn_v[o] + 1e-5f);
                sc[ii] = s;
                sh[ii] = bn_b[o] - bn_m[o] * s + bs[ii] * s;
            }
            #pragma unroll
            for (int ni = 0; ni < 2; ++ni) {
                int p = p0 + ni * 16 + col;
                #pragma unroll
                for (int ii = 0; ii < 4; ++ii)
                    outF[((size_t)(b * CH + ob + ii)) * P + p] =
                        acc[mi][ni][ii] * sc[ii] + sh[ii];
            }
        } else {
            #pragma unroll
            for (int ni = 0; ni < 2; ++ni) {
                int p = p0 + ni * 16 + col;
                float v0 = acc[mi][ni][0] + bs[0];
                float v1 = acc[mi][ni][1] + bs[1];
                float v2 = acc[mi][ni][2] + bs[2];
                float v3 = acc[mi][ni][3] + bs[3];
                if (MODE == 0) {
                    outF[((size_t)(b * CH + ob + 0)) * P + p] = v0;
                    outF[((size_t)(b * CH + ob + 1)) * P + p] = v1;
                    outF[((size_t)(b * CH + ob + 2)) * P + p] = v2;
                    outF[((size_t)(b * CH + ob + 3)) * P + p] = v3;
                    uint2 w;
                    w.x = (unsigned)f2bf(v0) | ((unsigned)f2bf(v1) << 16);
                    w.y = (unsigned)f2bf(v2) | ((unsigned)f2bf(v3) << 16);
                    *(uint2*)&outB[((size_t)(b * P + p)) * CH + ob] = w;
                } else { // MODE 1
                    if (mat == 0) {
                        uint2 w;
                        w.x = (unsigned)f2bf(v0) | ((unsigned)f2bf(v1) << 16);
                        w.y = (unsigned)f2bf(v2) | ((unsigned)f2bf(v3) << 16);
                        *(uint2*)&outB[((size_t)(b * P + p)) * CH + ob] = w;
                    } else {
                        outB2[((size_t)(b * CH + ob + 0)) * P + p] = f2bf(v0);
                        outB2[((size_t)(b * CH + ob + 1)) * P + p] = f2bf(v1);
                        outB2[((size_t)(b * CH + ob + 2)) * P + p] = f2bf(v2);
                        outB2[((size_t)(b * CH + ob + 3)) * P + p] = f2bf(v3);
                    }
                }
            }
        }
    }
}

// ---------------------------------------------------------------------------
// depthwise 9x9 conv, stride 2, pad 4 (q fp32 [b][c][32][32] -> off [b][c][16][16])
// ---------------------------------------------------------------------------
__global__ __launch_bounds__(256) void dwconv_k(
    const float* __restrict__ q, const float* __restrict__ w,
    const float* __restrict__ bias, float* __restrict__ off)
{
    int bc = blockIdx.x;
    int c  = bc & (CH - 1);
    __shared__ float plane[HW];
    __shared__ float kw[81];
    int t = threadIdx.x;
    const float* qp = q + (size_t)bc * HW;
    #pragma unroll
    for (int j = t; j < HW; j += 256) plane[j] = qp[j];
    if (t < 81) kw[t] = w[c * 81 + t];
    __syncthreads();
    int hk = t >> 4, wk = t & 15;
    float s = bias[c];
    int yb = hk * 2 - 4, xb = wk * 2 - 4;
    #pragma unroll
    for (int dy = 0; dy < 9; ++dy) {
        int yy = yb + dy;
        if ((unsigned)yy < 32u) {
            #pragma unroll
            for (int dx = 0; dx < 9; ++dx) {
                int xx = xb + dx;
                if ((unsigned)xx < 32u) s += kw[dy * 9 + dx] * plane[yy * 32 + xx];
            }
        }
    }
    off[(size_t)bc * NS + t] = s;
}

// ---------------------------------------------------------------------------
// fused: LN(channel) + GELU + projection + ref + tanh + bilinear grid sample
// block per (b,s); 256 threads = channels; pos never leaves the block.
// -> xsT bf16 [b][s][c]
// ---------------------------------------------------------------------------
__device__ inline void block_reduce2(float& a, float& b, int t, float* sbuf)
{
    #pragma unroll
    for (int o = 32; o > 0; o >>= 1) {
        a += __shfl_down(a, o);
        b += __shfl_down(b, o);
    }
    int w = t >> 6;
    if ((t & 63) == 0) { sbuf[w * 2] = a; sbuf[w * 2 + 1] = b; }
    __syncthreads();
    a = sbuf[0] + sbuf[2] + sbuf[4] + sbuf[6];
    b = sbuf[1] + sbuf[3] + sbuf[5] + sbuf[7];
    __syncthreads();
}

__global__ __launch_bounds__(256) void lngs_k(
    const float* __restrict__ off, const float* __restrict__ ln_g,
    const float* __restrict__ ln_b, const float* __restrict__ pw,
    const float* __restrict__ x, unsigned short* __restrict__ xsT)
{
    __shared__ float sbuf[8];
    int bs = blockIdx.x;
    int b = bs >> 8, s = bs & 255;
    int c = threadIdx.x;
    float v = off[((size_t)(b * CH + c)) * NS + s];
    float a = v, q2 = v * v;
    block_reduce2(a, q2, c, sbuf);
    float mean = a * (1.0f / 256.0f);
    float var  = q2 * (1.0f / 256.0f) - mean * mean;
    float xn = (v - mean) * rsqrtf(var + 1e-5f) * ln_g[c] + ln_b[c];
    float g = 0.5f * xn * (1.0f + erff(xn * 0.70710678118654752f));
    float d0 = g * pw[c];
    float d1 = g * pw[CH + c];
    block_reduce2(d0, d1, c, sbuf);   // broadcasts sums to all threads

    int hk = s >> 4, wk = s & 15;
    float ry = ((hk + 0.5f) / 16.0f) * 2.0f - 1.0f;
    float rx = ((wk + 0.5f) / 16.0f) * 2.0f - 1.0f;
    float py = tanhf(d0 + ry);
    float px = tanhf(d1 + rx);

    float gx = (px + 1.0f) * 0.5f * 31.0f;
    float gy = (py + 1.0f) * 0.5f * 31.0f;
    float x0f = floorf(gx), y0f = floorf(gy);
    int ix = (int)x0f, iy = (int)y0f;
    float wx1 = gx - x0f, wx0 = 1.0f - wx1;
    float wy1 = gy - y0f, wy0 = 1.0f - wy1;
    const float* img = x + ((size_t)b * CH + c) * HW;
    float v00 = ((unsigned)iy < 32u && (unsigned)ix < 32u) ? img[iy * 32 + ix] : 0.0f;
    float v01 = ((unsigned)iy < 32u && (unsigned)(ix + 1) < 32u) ? img[iy * 32 + ix + 1] : 0.0f;
    float v10 = ((unsigned)(iy + 1) < 32u && (unsigned)ix < 32u) ? img[(iy + 1) * 32 + ix] : 0.0f;
    float v11 = ((unsigned)(iy + 1) < 32u && (unsigned)(ix + 1) < 32u) ? img[(iy + 1) * 32 + ix + 1] : 0.0f;
    float vv = wy0 * wx0 * v00 + wy0 * wx1 * v01 + wy1 * wx0 * v10 + wy1 * wx1 * v11;
    xsT[(size_t)bs * CH + c] = f2bf(vv);
}

// ---------------------------------------------------------------------------
// MFMA attention (all-bf16 I/O). qT[b][m][c], kT[b][n][c], v[b][c][n] -> aoT[b][m][c]
// ---------------------------------------------------------------------------
__global__ __launch_bounds__(256) void attn_mfma_k(
    const unsigned short* __restrict__ qT, const unsigned short* __restrict__ kT,
    const unsigned short* __restrict__ vbf, unsigned short* __restrict__ aoT)
{
    const int bh   = blockIdx.x >> 2;
    const int mseg = blockIdx.x & 3;
    const int b = bh >> 4, h = bh & 15;

    __shared__ short Kp[16 * 64 * 8];   // A-frag order
    __shared__ short Vsh[16 * 256];     // [d][n], byte ^= (d&7)<<4
    __shared__ short Ps[4][16 * 32];    // per-wave P scratch, byte ^= (m&7)<<4

    const int tid  = threadIdx.x;
    const int lane = tid & 63;
    const int wvi  = tid >> 6;
    const int col  = lane & 15;
    const int g    = lane >> 4;

    for (int e = tid; e < 512; e += 256) {
        int t = e >> 5, l = e & 31, gg = l >> 4, c = l & 15;
        short8v kk = *(const short8v*)&kT[((size_t)(b * NS + 16 * t + c)) * CH + h * 16 + 8 * gg];
        *(short8v*)&Kp[(t * 64 + l) * 8] = kk;
        short8v z = {0, 0, 0, 0, 0, 0, 0, 0};
        *(short8v*)&Kp[(t * 64 + 32 + l) * 8] = z;
    }
    {
        const unsigned short* Vb = vbf + ((size_t)(b * CH + h * 16)) * NS;
        int d = tid >> 4, n0 = (tid & 15) * 16;
        char* vb = (char*)Vsh;
        #pragma unroll
        for (int hh = 0; hh < 2; ++hh) {
            short8v pk = *(const short8v*)&Vb[(size_t)d * NS + n0 + 8 * hh];
            *(short8v*)(vb + ((d * 512 + (n0 + 8 * hh) * 2) ^ ((d & 7) << 4))) = pk;
        }
    }
    __syncthreads();

    const unsigned short* Qb = qT + (size_t)b * HW * CH + h * 16;
    unsigned short*       Ob = aoT + (size_t)b * HW * CH + h * 16;
    char* pbase = (char*)Ps[wvi];
    char* vbase = (char*)Vsh;

    for (int mt = 0; mt < 4; ++mt) {
        const int m0 = mseg * 256 + wvi * 64 + mt * 16;

        short8v qf = {0, 0, 0, 0, 0, 0, 0, 0};
        if (g < 2)
            qf = *(const short8v*)&Qb[(size_t)(m0 + col) * CH + 8 * g];

        float4v p[16];
        #pragma unroll
        for (int t = 0; t < 16; ++t) {
            short8v kf = *(const short8v*)&Kp[(t * 64 + lane) * 8];
            float4v z = {0.f, 0.f, 0.f, 0.f};
            p[t] = __builtin_amdgcn_mfma_f32_16x16x32_bf16(kf, qf, z, 0, 0, 0);
        }

        float mx = -1e30f;
        #pragma unroll
        for (int t = 0; t < 16; ++t)
            mx = fmaxf(mx, fmaxf(fmaxf(p[t][0], p[t][1]), fmaxf(p[t][2], p[t][3])));
        mx = fmaxf(mx, __shfl_xor(mx, 16));
        mx = fmaxf(mx, __shfl_xor(mx, 32));
        float sum = 0.f;
        #pragma unroll
        for (int t = 0; t < 16; ++t) {
            #pragma unroll
            for (int i = 0; i < 4; ++i) {
                float e = __expf((p[t][i] - mx) * 0.25f);
                p[t][i] = e;
                sum += e;
            }
        }
        sum += __shfl_xor(sum, 16);
        sum += __shfl_xor(sum, 32);
        const float inv = 1.0f / sum;

        float4v acc = {0.f, 0.f, 0.f, 0.f};
        #pragma unroll
        for (int c = 0; c < 8; ++c) {
            #pragma unroll
            for (int pp = 0; pp < 2; ++pp) {
                float4v pv = p[2 * c + pp];
                uint2 wr;
                wr.x = (unsigned)f2bf(pv[0]) | ((unsigned)f2bf(pv[1]) << 16);
                wr.y = (unsigned)f2bf(pv[2]) | ((unsigned)f2bf(pv[3]) << 16);
                *(uint2*)(pbase + ((col * 64 + (16 * pp + 4 * g) * 2) ^ ((col & 7) << 4))) = wr;
            }
            short8v pf = *(const short8v*)(pbase + ((col * 64 + 16 * g) ^ ((col & 7) << 4)));
            short8v vf = *(const short8v*)(vbase + ((col * 512 + 64 * c + 16 * g) ^ ((col & 7) << 4)));
            acc = __builtin_amdgcn_mfma_f32_16x16x32_bf16(vf, pf, acc, 0, 0, 0);
        }

        uint2 w;
        w.x = (unsigned)f2bf(acc[0] * inv) | ((unsigned)f2bf(acc[1] * inv) << 16);
        w.y = (unsigned)f2bf(acc[2] * inv) | ((unsigned)f2bf(acc[3] * inv) << 16);
        *(uint2*)&Ob[(size_t)(m0 + col) * CH + 4 * g] = w;
    }
}

// ---------------------------------------------------------------------------
extern "C" void kernel_launch(void* const* d_in, const int* in_sizes, int n_in,
                              void* d_out, int out_size, void* d_ws, size_t ws_size,
                              hipStream_t stream)
{
    const float* x        = (const float*)d_in[0];
    const float* wq       = (const float*)d_in[1];
    const float* bq       = (const float*)d_in[2];
    const float* off_dw_w = (const float*)d_in[3];
    const float* off_dw_b = (const float*)d_in[4];
    const float* ln_g     = (const float*)d_in[5];
    const float* ln_b     = (const float*)d_in[6];
    const float* off_pw_w = (const float*)d_in[7];
    const float* wk       = (const float*)d_in[8];
    const float* bk       = (const float*)d_in[9];
    const float* wv       = (const float*)d_in[10];
    const float* bv       = (const float*)d_in[11];
    const float* wo       = (const float*)d_in[12];
    const float* bo       = (const float*)d_in[13];
    const float* bn_g     = (const float*)d_in[14];
    const float* bn_b     = (const float*)d_in[15];
    const float* bn_m     = (const float*)d_in[16];
    const float* bn_v     = (const float*)d_in[17];

    float* ws  = (float*)d_ws;
    float* q   = ws;                        // 4194304 f (q fp32 for dwconv)
    float* off = q + 4194304;               // 1048576 f
    unsigned short* us  = (unsigned short*)(off + 1048576);
    unsigned short* Wf  = us;               //  262144 us (4 frag-packed weights)
    unsigned short* xT  = Wf  + 262144;     // 4194304 us
    unsigned short* qT  = xT  + 4194304;    // 4194304 us
    unsigned short* xsT = qT  + 4194304;    // 1048576 us
    unsigned short* kT  = xsT + 1048576;    // 1048576 us
    unsigned short* vbf = kT  + 1048576;    // 1048576 us
    unsigned short* aoT = vbf + 1048576;    // 4194304 us

    prep_k<<<1280, 256, 0, stream>>>(wq, wk, wv, wo, Wf, x, xT);
    gemm_k<HW, 0><<<dim3(4, 8, BATCH), 256, 0, stream>>>(
        Wf, xT, bq, nullptr, q, qT, nullptr, nullptr, nullptr, nullptr, nullptr);
    dwconv_k<<<BATCH * CH, 256, 0, stream>>>(q, off_dw_w, off_dw_b, off);
    lngs_k<<<BATCH * NS, 256, 0, stream>>>(off, ln_g, ln_b, off_pw_w, x, xsT);
    gemm_k<NS, 1><<<dim3(4, 2, 2 * BATCH), 256, 0, stream>>>(
        Wf + 65536, xsT, bk, bv, nullptr, kT, vbf, nullptr, nullptr, nullptr, nullptr);
    attn_mfma_k<<<BATCH * NH * 4, 256, 0, stream>>>(qT, kT, vbf, aoT);
    gemm_k<HW, 2><<<dim3(4, 8, BATCH), 256, 0, stream>>>(
        Wf + 3 * 65536, aoT, bo, nullptr, (float*)d_out, nullptr, nullptr,
        bn_g, bn_b, bn_m, bn_v);
}